// Round 1
// baseline (1141.861 us; speedup 1.0000x reference)
//
#include <hip/hip_runtime.h>
#include <stdint.h>

#define EPS 1e-5f

typedef __attribute__((ext_vector_type(8))) __bf16 bf16x8;
typedef __attribute__((ext_vector_type(8))) unsigned short ushort8;
typedef __attribute__((ext_vector_type(4))) float f32x4;

__device__ __forceinline__ unsigned short f2bf(float f) {
    union { float f; unsigned u; } c; c.f = f;
    unsigned r = c.u + 0x7fffu + ((c.u >> 16) & 1u);   // RNE truncate to bf16
    return (unsigned short)(r >> 16);
}

// ---- pass 1: per-channel sum / sumsq ------------------------------------
__global__ void stats_kernel(const float* __restrict__ f, float* __restrict__ ws, int n) {
    __shared__ float s_sum[32];
    __shared__ float s_sq[32];
    int tid = threadIdx.x;
    if (tid < 32) { s_sum[tid] = 0.f; s_sq[tid] = 0.f; }
    __syncthreads();
    int c = tid & 31;          // channel
    int g = tid >> 5;          // row-group within block (8 rows/block/step)
    float sum = 0.f, sq = 0.f;
    for (int r = blockIdx.x * 8 + g; r < n; r += gridDim.x * 8) {
        float v = f[(size_t)r * 32 + c];
        sum += v; sq += v * v;
    }
    atomicAdd(&s_sum[c], sum);
    atomicAdd(&s_sq[c], sq);
    __syncthreads();
    if (tid < 32) {
        atomicAdd(&ws[tid],      s_sum[tid]);
        atomicAdd(&ws[32 + tid], s_sq[tid]);
    }
}

// ---- pass 2: fold BN into per-channel scale/shift -----------------------
__global__ void finalize_kernel(const float* __restrict__ gamma, const float* __restrict__ beta,
                                float* __restrict__ ws, int n) {
    int c = threadIdx.x;
    if (c < 32) {
        float inv_n = 1.f / (float)n;
        float mean = ws[c] * inv_n;
        float var  = ws[32 + c] * inv_n - mean * mean;   // biased var
        float scale = gamma[c] * rsqrtf(var + EPS);
        ws[64 + c] = scale;                 // x*scale + shift == BN(x)
        ws[96 + c] = beta[c] - mean * scale;
    }
}

// ---- pass 3: normalize + relu + masked-MFMA conv + atomic scatter -------
// One wave handles 16 consecutive points. All 8 taps are run as masked
// mfma_f32_16x16x32_bf16 into shared accumulators (each point matches
// exactly one tap). W lives in VGPRs (8 taps x 4 ch-blocks x 8 bf16/lane).
__global__ __launch_bounds__(256, 2) void spconv_kernel(
    const float* __restrict__ feat, const float* __restrict__ weight,
    const int* __restrict__ out_idx, const int* __restrict__ off_idx,
    const float* __restrict__ ws, float* __restrict__ out, int n)
{
    const int lane = threadIdx.x & 63;
    const int m    = lane & 15;     // A/D row (point) and B/D col (channel) index
    const int quad = lane >> 4;     // k-quad
    const int wave   = blockIdx.x * (blockDim.x >> 6) + (threadIdx.x >> 6);
    const int nwaves = gridDim.x * (blockDim.x >> 6);

    // per-lane BN scale/shift for k = quad*8 + j (loop-invariant)
    float scl[8], sft[8];
    #pragma unroll
    for (int j = 0; j < 8; ++j) {
        int k = quad * 8 + j;
        scl[j] = ws[64 + k];
        sft[j] = ws[96 + k];
    }

    // W fragments (B-layout): B[k][nch], k = quad*8+j, nch = cb*16+m
    ushort8 wf[8][4];
    #pragma unroll
    for (int t = 0; t < 8; ++t) {
        #pragma unroll
        for (int cb = 0; cb < 4; ++cb) {
            ushort8 v;
            #pragma unroll
            for (int j = 0; j < 8; ++j) {
                int k = quad * 8 + j;
                v[j] = f2bf(weight[((size_t)t * 32 + k) * 64 + cb * 16 + m]);
            }
            wf[t][cb] = v;
        }
    }

    const ushort8 zz = {0, 0, 0, 0, 0, 0, 0, 0};
    const int ntiles = (n + 15) >> 4;

    for (int tile = wave; tile < ntiles; tile += nwaves) {
        const int p_base = tile << 4;
        const int p  = p_base + m;
        const int pc = p < n ? p : n - 1;

        // load this lane's 8 k-values of point m: 2 x dwordx4, dense 2KB/wave
        const f32x4* fp = (const f32x4*)(feat + (size_t)pc * 32 + quad * 8);
        f32x4 x0 = fp[0];
        f32x4 x1 = fp[1];

        // BN + ReLU + bf16 convert into A-fragment
        ushort8 af;
        #pragma unroll
        for (int j = 0; j < 4; ++j)
            af[j] = f2bf(fmaxf(x0[j] * scl[j] + sft[j], 0.f));
        #pragma unroll
        for (int j = 0; j < 4; ++j)
            af[4 + j] = f2bf(fmaxf(x1[j] * scl[4 + j] + sft[4 + j], 0.f));

        const int tap = (p < n) ? off_idx[p] : -1;

        f32x4 acc[4];
        #pragma unroll
        for (int cb = 0; cb < 4; ++cb) acc[cb] = (f32x4){0.f, 0.f, 0.f, 0.f};

        // 8 taps, masked A; each point contributes on exactly one tap
        #pragma unroll
        for (int t = 0; t < 8; ++t) {
            ushort8 am = (tap == t) ? af : zz;   // 4 v_cndmask
            bf16x8 a = __builtin_bit_cast(bf16x8, am);
            #pragma unroll
            for (int cb = 0; cb < 4; ++cb) {
                acc[cb] = __builtin_amdgcn_mfma_f32_16x16x32_bf16(
                    a, __builtin_bit_cast(bf16x8, wf[t][cb]), acc[cb], 0, 0, 0);
            }
        }

        // scatter: D row = quad*4 + i (point), col = cb*16 + m (channel)
        int o[4]; bool ok[4];
        #pragma unroll
        for (int i = 0; i < 4; ++i) {
            int pr = p_base + quad * 4 + i;
            ok[i] = pr < n;
            o[i]  = ok[i] ? out_idx[pr] : 0;
        }
        #pragma unroll
        for (int cb = 0; cb < 4; ++cb) {
            #pragma unroll
            for (int i = 0; i < 4; ++i) {
                if (ok[i])
                    atomicAdd(out + (size_t)o[i] * 64 + cb * 16 + m, acc[cb][i]);
            }
        }
    }
}

extern "C" void kernel_launch(void* const* d_in, const int* in_sizes, int n_in,
                              void* d_out, int out_size, void* d_ws, size_t ws_size,
                              hipStream_t stream) {
    const float* features  = (const float*)d_in[0];
    const float* gamma     = (const float*)d_in[1];
    const float* beta      = (const float*)d_in[2];
    const float* weight    = (const float*)d_in[3];
    const int*   out_index = (const int*)d_in[4];
    const int*   off_index = (const int*)d_in[5];
    float* out = (float*)d_out;
    float* ws  = (float*)d_ws;
    const int n = in_sizes[0] / 32;

    // out must start at zero (harness poisons 0xAA); ws[0:64] holds sums
    hipMemsetAsync(d_out, 0, (size_t)out_size * sizeof(float), stream);
    hipMemsetAsync(d_ws, 0, 64 * sizeof(float), stream);

    stats_kernel<<<2048, 256, 0, stream>>>(features, ws, n);
    finalize_kernel<<<1, 64, 0, stream>>>(gamma, beta, ws, n);
    spconv_kernel<<<1024, 256, 0, stream>>>(features, weight, out_index, off_index,
                                            ws, out, n);
}